// Round 1
// 243.833 us; speedup vs baseline: 1.0162x; 1.0162x over previous
//
#include <hip/hip_runtime.h>

// Problem constants
#define NB 16
#define NH 96
#define NW 320
#define NCIN 32

#define FC_K 61440
#define FC_KC 120          // k per chunk
#define FC_NCHUNK 512      // 512 * 120 = 61440; 512 blocks = 2/CU exactly

typedef __attribute__((ext_vector_type(8))) short short8;     // 8 bf16 (4 VGPRs)
typedef __attribute__((ext_vector_type(4))) float f32x4;

__device__ inline unsigned short f2bf(float f) {
    union { float f; unsigned int u; } v; v.f = f;
    unsigned int r = v.u + 0x7FFF + ((v.u >> 16) & 1);   // RNE
    return (unsigned short)(r >> 16);
}

// ---------------------------------------------------------------------------
// Fused setup kernel.
// Blocks [0,396): weight fragments OIHW fp32 -> MFMA B-operand bf16,
//   wf[((kk*NT + nt)*64 + lane)*8 + j], oc = nt*16+(lane&15),
//   ic = ks*32+(lane>>4)*8+j  [m91-verified map]
// Blocks [396,...): scatter+cast active cells from fp32 input into the
//   (memset-zeroed) dense bf16 input. Reads ONLY active cells (~25.6 MB).
//   4 threads per coord, 8 ch each; duplicates write identical bytes.
// ---------------------------------------------------------------------------
__global__ __launch_bounds__(256) void setup_all(const float* __restrict__ w1,
                                                 const float* __restrict__ w2,
                                                 const float* __restrict__ w3,
                                                 unsigned short* __restrict__ f1,
                                                 unsigned short* __restrict__ f2,
                                                 unsigned short* __restrict__ f3,
                                                 const int* __restrict__ coords,
                                                 const float* __restrict__ input,
                                                 unsigned short* __restrict__ inBf,
                                                 int n) {
    if (blockIdx.x < 396) {
        int i = blockIdx.x * 256 + threadIdx.x;
        if (i < 9216) {                       // conv1: IC=32 OC=32 NT=2 KS=1
            int j = i & 7, lane = (i >> 3) & 63, nt = (i >> 9) & 1, tap = i >> 10;
            int ic = ((lane >> 4) * 8) + j, oc = nt * 16 + (lane & 15);
            f1[i] = f2bf(w1[(oc * 32 + ic) * 9 + tap]);
        } else if (i < 27648) {               // conv2: IC=32 OC=64 NT=4 KS=1
            int v = i - 9216;
            int j = v & 7, lane = (v >> 3) & 63, nt = (v >> 9) & 3, tap = v >> 11;
            int ic = ((lane >> 4) * 8) + j, oc = nt * 16 + (lane & 15);
            f2[v] = f2bf(w2[(oc * 32 + ic) * 9 + tap]);
        } else if (i < 101376) {              // conv3: IC=64 OC=128 NT=8 KS=2
            int v = i - 27648;
            int j = v & 7, lane = (v >> 3) & 63, nt = (v >> 9) & 7, kk = v >> 12;
            int tap = kk >> 1, ks = kk & 1;
            int ic = ks * 32 + ((lane >> 4) * 8) + j, oc = nt * 16 + (lane & 15);
            f3[v] = f2bf(w3[(oc * 64 + ic) * 9 + tap]);
        }
    } else {
        int i = (blockIdx.x - 396) * 256 + threadIdx.x;
        if (i >= n * 4) return;
        int ci = i >> 2, q = i & 3;
        int b = coords[ci * 3 + 0], y = coords[ci * 3 + 1], x = coords[ci * 3 + 2];
        long base = ((long)((b * NH + y) * NW + x)) * NCIN + q * 8;
        const float4* src = (const float4*)(input + base);
        float4 v0 = src[0], v1 = src[1];
        union { short8 s8; unsigned short us[8]; } o;
        o.us[0] = f2bf(v0.x); o.us[1] = f2bf(v0.y); o.us[2] = f2bf(v0.z); o.us[3] = f2bf(v0.w);
        o.us[4] = f2bf(v1.x); o.us[5] = f2bf(v1.y); o.us[6] = f2bf(v1.z); o.us[7] = f2bf(v1.w);
        *(short8*)(inBf + base) = o.s8;
    }
}

// ---------------------------------------------------------------------------
// Implicit-GEMM conv 3x3 stride-2 pad-1 via bf16 MFMA (16x16x32), bf16 NHWC in.
// Each wave: one 16-position strip x NL oc-tiles. A-fragments loaded ONCE
// per ks (9 x 16 B/lane, unconditional, addr clamped to cell 0, reg-reg
// cndmask -- R8 lesson), reused for NL*9 MFMAs (R9/R10 lesson: oc-tile
// duplication of the scattered gather was the stall). B-frag loads coalesced
// 1KB/wave, L1-hot, in-loop. acc indices compile-time (R4), ks loop unroll 1
// (R2). Layouts m89/m91: A[m=lane&15][k=quad*8+j], D[row=quad*4+reg][col=lane&15].
// ---------------------------------------------------------------------------
template<int IC, int OC, int NL, int IH, int IW, int OH, int OW>
__global__ __launch_bounds__(256) void conv_mfma(
    const unsigned short* __restrict__ inPtr,  // NHWC bf16
    const unsigned short* __restrict__ wfrag,  // B-fragments bf16
    const float* __restrict__ bias,
    float* __restrict__ out)                   // NHWC fp32 (pre-relu)
{
    constexpr int KS = IC / 32;
    constexpr int NT = OC / 16;
    constexpr int NG = NT / NL;                // wave-groups per strip
    constexpr int NSTRIPS = NB * OH * OW / 16;

    const int wid  = (blockIdx.x * 256 + threadIdx.x) >> 6;
    const int lane = threadIdx.x & 63;
    const int ntb  = (wid % NG) * NL;
    const int s    = wid / NG;
    if (s >= NSTRIPS) return;
    const int quad = lane >> 4;
    const int lm   = lane & 15;

    const int p0 = s * 16;
    const int posA = p0 + lm;
    const int b  = posA / (OH * OW);
    const int rr = posA % (OH * OW);
    const int oy = rr / OW, ox = rr % OW;
    const int iy0 = oy * 2 - 1, ix0 = ox * 2 - 1;

    int cell[9];
    bool okb[9];
    #pragma unroll
    for (int t9 = 0; t9 < 9; t9++) {
        const int iy = iy0 + t9 / 3;
        const int ix = ix0 + t9 % 3;
        const bool ok = (iy >= 0) && (iy < IH) && (ix >= 0) && (ix < IW);
        cell[t9] = ok ? ((b * IH + iy) * IW + ix) : 0;   // clamp addr, not load
        okb[t9] = ok;
    }

    short8 zero8;
    #pragma unroll
    for (int j = 0; j < 8; j++) zero8[j] = 0;

    f32x4 acc[NL][2];
    #pragma unroll
    for (int nl = 0; nl < NL; nl++)
        #pragma unroll
        for (int pp = 0; pp < 2; pp++)
            acc[nl][pp] = (f32x4){0.f, 0.f, 0.f, 0.f};

    #pragma unroll 1
    for (int ks = 0; ks < KS; ks++) {
        short8 av[9];
        #pragma unroll
        for (int t9 = 0; t9 < 9; t9++) {
            short8 v = *(const short8*)(inPtr + (long)cell[t9] * IC + ks * 32 + quad * 8);
            av[t9] = okb[t9] ? v : zero8;      // reg-reg cndmask
        }
        #pragma unroll
        for (int nl = 0; nl < NL; nl++) {
            #pragma unroll
            for (int t9 = 0; t9 < 9; t9++) {
                short8 bf = *(const short8*)(wfrag + (((t9 * KS + ks) * NT + ntb + nl) * 64 + lane) * 8);
                if (t9 & 1) acc[nl][1] = __builtin_amdgcn_mfma_f32_16x16x32_bf16(av[t9], bf, acc[nl][1], 0, 0, 0);
                else        acc[nl][0] = __builtin_amdgcn_mfma_f32_16x16x32_bf16(av[t9], bf, acc[nl][0], 0, 0, 0);
            }
        }
    }

    const long rowBase = (long)p0 + quad * 4;   // D: row=(lane>>4)*4+reg
    #pragma unroll
    for (int nl = 0; nl < NL; nl++) {
        const int oc = (ntb + nl) * 16 + lm;
        const float bv = bias[oc];
        #pragma unroll
        for (int reg = 0; reg < 4; reg++)
            out[(rowBase + reg) * OC + oc] = acc[nl][0][reg] + acc[nl][1][reg] + bv;
    }
}

// ---------------------------------------------------------------------------
// 3x3 stride-1 pad-1 maxpool (-inf pad) + ReLU, NHWC. fp32 in; bf16 or fp32
// out (bf16 feeds the next conv's MFMA A-operand).
// ---------------------------------------------------------------------------
template<int C, int HH, int WW, bool BF16OUT>
__global__ __launch_bounds__(256) void maxpool3_relu(const float* __restrict__ in, void* __restrict__ outv) {
    constexpr int C4 = C / 4;
    int i = blockIdx.x * blockDim.x + threadIdx.x;
    if (i >= NB * HH * WW * C4) return;
    int c = i % C4;
    int x = (i / C4) % WW;
    int y = (i / (C4 * WW)) % HH;
    int b = i / (C4 * WW * HH);
    float4 m = make_float4(-3.0e38f, -3.0e38f, -3.0e38f, -3.0e38f);
    #pragma unroll
    for (int dy = -1; dy <= 1; dy++) {
        int yy = y + dy;
        if (yy < 0 || yy >= HH) continue;
        #pragma unroll
        for (int dx = -1; dx <= 1; dx++) {
            int xx = x + dx;
            if (xx < 0 || xx >= WW) continue;
            float4 v = ((const float4*)in)[((b * HH + yy) * WW + xx) * C4 + c];
            m.x = fmaxf(m.x, v.x);
            m.y = fmaxf(m.y, v.y);
            m.z = fmaxf(m.z, v.z);
            m.w = fmaxf(m.w, v.w);
        }
    }
    m.x = fmaxf(m.x, 0.f);
    m.y = fmaxf(m.y, 0.f);
    m.z = fmaxf(m.z, 0.f);
    m.w = fmaxf(m.w, 0.f);
    if (BF16OUT) {
        ushort4 o;
        o.x = f2bf(m.x); o.y = f2bf(m.y); o.z = f2bf(m.z); o.w = f2bf(m.w);
        ((ushort4*)outv)[i] = o;
    } else {
        ((float4*)outv)[i] = m;
    }
}

// ---------------------------------------------------------------------------
// LDS-tiled permute: in[b][pos][c] (NHWC pooled3 fp32, pos=480,c=128) ->
// xT[c*480+pos][b]. Both sides coalesced float4.
// ---------------------------------------------------------------------------
__global__ __launch_bounds__(256) void transpose_fc(const float* __restrict__ in, float* __restrict__ xT) {
    __shared__ float tile_s[32 * 16 * 17];    // [c_l][pos_l][b(pad 17)]
    const int pt = blockIdx.x % 30;
    const int ct = blockIdx.x / 30;
    const int pos0 = pt * 16, c0 = ct * 32;
    const int t = threadIdx.x;
    {
        const int b = t / 16, pl = t % 16;
        const float4* src = (const float4*)(in + ((long)(b * 480 + pos0 + pl)) * 128 + c0);
        #pragma unroll
        for (int q = 0; q < 8; q++) {
            float4 v = src[q];
            tile_s[((4 * q + 0) * 16 + pl) * 17 + b] = v.x;
            tile_s[((4 * q + 1) * 16 + pl) * 17 + b] = v.y;
            tile_s[((4 * q + 2) * 16 + pl) * 17 + b] = v.z;
            tile_s[((4 * q + 3) * 16 + pl) * 17 + b] = v.w;
        }
    }
    __syncthreads();
    {
        const int w = t / 64, l = t % 64;
        const int pl2 = l / 4, b4 = l % 4;
        #pragma unroll
        for (int i = 0; i < 8; i++) {
            int cl = w + 4 * i;
            const float* ls = &tile_s[(cl * 16 + pl2) * 17 + 4 * b4];
            float4 v = make_float4(ls[0], ls[1], ls[2], ls[3]);
            *(float4*)(xT + ((long)(c0 + cl) * 480 + pos0 + pl2) * 16 + 4 * b4) = v;
        }
    }
}

// ---------------------------------------------------------------------------
// FC main (R11 rewrite): thread<->oc mapping, block<->k-chunk.
// Old fc_stage1 was latency/LLC-bound: lane<->k mapping forced per-LANE xT
// reads (64 B/lane scattered, 64x re-read = 251 MB through L2/LLC) and 4 B
// scalar weight loads -> 1.5 TB/s, VALUBusy 11%. Here:
//  - x[k][0..15] is wave-UNIFORM -> compiler scalarizes to s_load (SGPR
//    broadcast, constant cache). xT read ONCE total (3.9 MB, not 251 MB).
//  - each thread streams its oc's contiguous 480 B weight segment as 30
//    float4 loads issued up front (~30 KB/wave in flight) -> pure HBM stream,
//    every 64 B line fully consumed. Weights read once (63 MB, the floor).
//  - 512 chunks x 120 k = exactly 2 blocks/CU, balanced.
// Partials [chunk][oc*16+b] written non-atomic (8.4 MB), reduced below.
// All acc/w indices compile-time (R4 scratch lesson).
// ---------------------------------------------------------------------------
__global__ __launch_bounds__(256) void fc_main(const float* __restrict__ xT,
                                               const float* __restrict__ fw,
                                               float* __restrict__ partial)
{
    const int c  = blockIdx.x;           // 512 chunks
    const int oc = threadIdx.x;          // 256 output channels
    const int k0 = c * FC_KC;

    const float4* wp = (const float4*)(fw + (long)oc * FC_K + k0);  // 480 B, 16B-aligned
    float4 w[30];
    #pragma unroll
    for (int i = 0; i < 30; i++) w[i] = wp[i];

    float acc[16];
    #pragma unroll
    for (int b = 0; b < 16; b++) acc[b] = 0.f;

    const float* xb = xT + (long)k0 * 16;
    #pragma unroll
    for (int g = 0; g < 30; g++) {
        #pragma unroll
        for (int j = 0; j < 4; j++) {
            const float wv = (j == 0) ? w[g].x : (j == 1) ? w[g].y : (j == 2) ? w[g].z : w[g].w;
            const float* xp = xb + (g * 4 + j) * 16;   // wave-uniform address
            #pragma unroll
            for (int b = 0; b < 16; b++)
                acc[b] = fmaf(wv, xp[b], acc[b]);
        }
    }

    float4* pp = (float4*)(partial + ((long)c * 256 + oc) * 16);
    pp[0] = make_float4(acc[0],  acc[1],  acc[2],  acc[3]);
    pp[1] = make_float4(acc[4],  acc[5],  acc[6],  acc[7]);
    pp[2] = make_float4(acc[8],  acc[9],  acc[10], acc[11]);
    pp[3] = make_float4(acc[12], acc[13], acc[14], acc[15]);
}

// ---------------------------------------------------------------------------
// FC reduce: 256 blocks (one oc each) x 256 threads. Thread (b=t&15,
// stripe=t>>4) sums 32 chunks; 16x16 LDS tree finishes. Reads 8.4 MB wide
// (1024 waves) -- the old 32-thread serial version would be latency-bound.
// ---------------------------------------------------------------------------
__global__ __launch_bounds__(256) void fc_reduce(const float* __restrict__ partial,
                                                 const float* __restrict__ fcb,
                                                 float* __restrict__ out)
{
    __shared__ float red[16][17];
    const int oc = blockIdx.x;             // 256
    const int ol = threadIdx.x & 15;       // b
    const int st = threadIdx.x >> 4;       // chunk stripe
    float s = 0.f;
    #pragma unroll
    for (int j = 0; j < 32; j++)           // c = st + 16*j covers 0..511
        s += partial[(long)(st + 16 * j) * 4096 + oc * 16 + ol];
    red[st][ol] = s;
    __syncthreads();
    if (threadIdx.x < 16) {
        float tot = fcb[oc];
        #pragma unroll
        for (int k = 0; k < 16; k++) tot += red[k][threadIdx.x];
        out[threadIdx.x * 256 + oc] = fmaxf(tot, 0.f);   // out[b][oc]
    }
}

// ---------------------------------------------------------------------------
extern "C" void kernel_launch(void* const* d_in, const int* in_sizes, int n_in,
                              void* d_out, int out_size, void* d_ws, size_t ws_size,
                              hipStream_t stream) {
    const float* input  = (const float*)d_in[0];
    const int*   coords = (const int*)d_in[1];
    const float* w1 = (const float*)d_in[2];
    const float* b1 = (const float*)d_in[3];
    const float* w2 = (const float*)d_in[4];
    const float* b2 = (const float*)d_in[5];
    const float* w3 = (const float*)d_in[6];
    const float* b3 = (const float*)d_in[7];
    const float* fcw = (const float*)d_in[8];
    const float* fcb = (const float*)d_in[9];
    float* outp = (float*)d_out;

    const int n_active = in_sizes[1] / 3;

    // ---- workspace layout (~63.7 MB total) ----
    char* ws = (char*)d_ws;
    unsigned short* wf1 = (unsigned short*)ws;            // 18,432 B
    unsigned short* wf2 = wf1 + 9216;                     // 36,864 B
    unsigned short* wf3 = wf2 + 18432;                    // 147,456 B
    unsigned short* inBf = (unsigned short*)(ws + 204800);        // 31,457,280 B (16*96*320*32 bf16)
    char* regA = ws + 204800 + 31457280;                  // 15,728,640 B
    char* regB = regA + 15728640;                         // 7,864,320 B
    float* partial = (float*)(regB + 7864320);            // 8,388,608 B (512*4096*4)

    // ping-pong aliasing (stream-ordered, each buffer dead before reuse):
    float*          conv1o  = (float*)regA;           // 15.73 MB fp32
    unsigned short* pool1bf = (unsigned short*)regB;   //  7.86 MB bf16
    float*          conv2o  = (float*)regA;           //  7.86 MB fp32
    unsigned short* pool2bf = (unsigned short*)regB;   //  3.93 MB bf16
    float*          conv3o  = (float*)regA;           //  3.93 MB fp32
    float*          pool3f  = (float*)regB;           //  3.93 MB fp32
    float*          xT      = (float*)regA;           //  3.93 MB fp32

    // zero dense bf16 input (31,457,280 B -- R7's bug was undersizing this),
    // then fused wfrag-prep + scatter-cast of active cells only.
    hipMemsetAsync(inBf, 0, 31457280, stream);
    const int scatterBlocks = (n_active * 4 + 255) / 256;
    setup_all<<<396 + scatterBlocks, 256, 0, stream>>>(w1, w2, w3, wf1, wf2, wf3,
                                                       coords, input, inBf, n_active);

    // conv1: (16,96,320,32)->(16,48,160,32); NT=2 NL=2 -> 7680 waves
    conv_mfma<32, 32, 2, 96, 320, 48, 160>
        <<<1920, 256, 0, stream>>>(inBf, wf1, b1, conv1o);
    maxpool3_relu<32, 48, 160, true><<<3840, 256, 0, stream>>>(conv1o, pool1bf);

    // conv2: (16,48,160,32)->(16,24,80,64); NT=4 NL=2 -> 3840 waves
    conv_mfma<32, 64, 2, 48, 160, 24, 80>
        <<<960, 256, 0, stream>>>(pool1bf, wf2, b2, conv2o);
    maxpool3_relu<64, 24, 80, true><<<1920, 256, 0, stream>>>(conv2o, pool2bf);

    // conv3: (16,24,80,64)->(16,12,40,128); NT=8 NL=2 -> 1920 waves
    conv_mfma<64, 128, 2, 24, 80, 12, 40>
        <<<480, 256, 0, stream>>>(pool2bf, wf3, b3, conv3o);
    maxpool3_relu<128, 12, 40, false><<<960, 256, 0, stream>>>(conv3o, pool3f);

    // flatten permute + FC (fp32, exact weights; read-once both streams)
    transpose_fc<<<120, 256, 0, stream>>>(pool3f, xT);
    fc_main<<<FC_NCHUNK, 256, 0, stream>>>(xT, fcw, partial);
    fc_reduce<<<256, 256, 0, stream>>>(partial, fcb, outp);
}

// Round 2
// 242.351 us; speedup vs baseline: 1.0224x; 1.0061x over previous
//
#include <hip/hip_runtime.h>

// Problem constants
#define NB 16
#define NH 96
#define NW 320
#define NCIN 32

#define FC_K 61440
#define FC_KC 120          // k per chunk
#define FC_NCHUNK 512      // 512 * 120 = 61440; 512 blocks = 2/CU exactly

typedef __attribute__((ext_vector_type(8))) short short8;     // 8 bf16 (4 VGPRs)
typedef __attribute__((ext_vector_type(4))) float f32x4;

__device__ inline unsigned short f2bf(float f) {
    union { float f; unsigned int u; } v; v.f = f;
    unsigned int r = v.u + 0x7FFF + ((v.u >> 16) & 1);   // RNE
    return (unsigned short)(r >> 16);
}

// ---------------------------------------------------------------------------
// Fused setup kernel.
// Blocks [0,396): weight fragments OIHW fp32 -> MFMA B-operand bf16,
//   wf[((kk*NT + nt)*64 + lane)*8 + j], oc = nt*16+(lane&15),
//   ic = ks*32+(lane>>4)*8+j  [m91-verified map]
// Blocks [396,...): scatter+cast active cells from fp32 input into the
//   (memset-zeroed) dense bf16 input. Reads ONLY active cells (~25.6 MB).
//   4 threads per coord, 8 ch each; duplicates write identical bytes.
// ---------------------------------------------------------------------------
__global__ __launch_bounds__(256) void setup_all(const float* __restrict__ w1,
                                                 const float* __restrict__ w2,
                                                 const float* __restrict__ w3,
                                                 unsigned short* __restrict__ f1,
                                                 unsigned short* __restrict__ f2,
                                                 unsigned short* __restrict__ f3,
                                                 const int* __restrict__ coords,
                                                 const float* __restrict__ input,
                                                 unsigned short* __restrict__ inBf,
                                                 int n) {
    if (blockIdx.x < 396) {
        int i = blockIdx.x * 256 + threadIdx.x;
        if (i < 9216) {                       // conv1: IC=32 OC=32 NT=2 KS=1
            int j = i & 7, lane = (i >> 3) & 63, nt = (i >> 9) & 1, tap = i >> 10;
            int ic = ((lane >> 4) * 8) + j, oc = nt * 16 + (lane & 15);
            f1[i] = f2bf(w1[(oc * 32 + ic) * 9 + tap]);
        } else if (i < 27648) {               // conv2: IC=32 OC=64 NT=4 KS=1
            int v = i - 9216;
            int j = v & 7, lane = (v >> 3) & 63, nt = (v >> 9) & 3, tap = v >> 11;
            int ic = ((lane >> 4) * 8) + j, oc = nt * 16 + (lane & 15);
            f2[v] = f2bf(w2[(oc * 32 + ic) * 9 + tap]);
        } else if (i < 101376) {              // conv3: IC=64 OC=128 NT=8 KS=2
            int v = i - 27648;
            int j = v & 7, lane = (v >> 3) & 63, nt = (v >> 9) & 7, kk = v >> 12;
            int tap = kk >> 1, ks = kk & 1;
            int ic = ks * 32 + ((lane >> 4) * 8) + j, oc = nt * 16 + (lane & 15);
            f3[v] = f2bf(w3[(oc * 64 + ic) * 9 + tap]);
        }
    } else {
        int i = (blockIdx.x - 396) * 256 + threadIdx.x;
        if (i >= n * 4) return;
        int ci = i >> 2, q = i & 3;
        int b = coords[ci * 3 + 0], y = coords[ci * 3 + 1], x = coords[ci * 3 + 2];
        long base = ((long)((b * NH + y) * NW + x)) * NCIN + q * 8;
        const float4* src = (const float4*)(input + base);
        float4 v0 = src[0], v1 = src[1];
        union { short8 s8; unsigned short us[8]; } o;
        o.us[0] = f2bf(v0.x); o.us[1] = f2bf(v0.y); o.us[2] = f2bf(v0.z); o.us[3] = f2bf(v0.w);
        o.us[4] = f2bf(v1.x); o.us[5] = f2bf(v1.y); o.us[6] = f2bf(v1.z); o.us[7] = f2bf(v1.w);
        *(short8*)(inBf + base) = o.s8;
    }
}

// ---------------------------------------------------------------------------
// Implicit-GEMM conv 3x3 stride-2 pad-1 via bf16 MFMA (16x16x32), bf16 NHWC in.
// Each wave: one 16-position strip x NL oc-tiles. A-fragments loaded ONCE
// per ks (9 x 16 B/lane, unconditional, addr clamped to cell 0, reg-reg
// cndmask -- R8 lesson), reused for NL*9 MFMAs (R9/R10 lesson: oc-tile
// duplication of the scattered gather was the stall). B-frag loads coalesced
// 1KB/wave, L1-hot, in-loop. acc indices compile-time (R4), ks loop unroll 1
// (R2). Layouts m89/m91: A[m=lane&15][k=quad*8+j], D[row=quad*4+reg][col=lane&15].
// ---------------------------------------------------------------------------
template<int IC, int OC, int NL, int IH, int IW, int OH, int OW>
__global__ __launch_bounds__(256) void conv_mfma(
    const unsigned short* __restrict__ inPtr,  // NHWC bf16
    const unsigned short* __restrict__ wfrag,  // B-fragments bf16
    const float* __restrict__ bias,
    float* __restrict__ out)                   // NHWC fp32 (pre-relu)
{
    constexpr int KS = IC / 32;
    constexpr int NT = OC / 16;
    constexpr int NG = NT / NL;                // wave-groups per strip
    constexpr int NSTRIPS = NB * OH * OW / 16;

    const int wid  = (blockIdx.x * 256 + threadIdx.x) >> 6;
    const int lane = threadIdx.x & 63;
    const int ntb  = (wid % NG) * NL;
    const int s    = wid / NG;
    if (s >= NSTRIPS) return;
    const int quad = lane >> 4;
    const int lm   = lane & 15;

    const int p0 = s * 16;
    const int posA = p0 + lm;
    const int b  = posA / (OH * OW);
    const int rr = posA % (OH * OW);
    const int oy = rr / OW, ox = rr % OW;
    const int iy0 = oy * 2 - 1, ix0 = ox * 2 - 1;

    int cell[9];
    bool okb[9];
    #pragma unroll
    for (int t9 = 0; t9 < 9; t9++) {
        const int iy = iy0 + t9 / 3;
        const int ix = ix0 + t9 % 3;
        const bool ok = (iy >= 0) && (iy < IH) && (ix >= 0) && (ix < IW);
        cell[t9] = ok ? ((b * IH + iy) * IW + ix) : 0;   // clamp addr, not load
        okb[t9] = ok;
    }

    short8 zero8;
    #pragma unroll
    for (int j = 0; j < 8; j++) zero8[j] = 0;

    f32x4 acc[NL][2];
    #pragma unroll
    for (int nl = 0; nl < NL; nl++)
        #pragma unroll
        for (int pp = 0; pp < 2; pp++)
            acc[nl][pp] = (f32x4){0.f, 0.f, 0.f, 0.f};

    #pragma unroll 1
    for (int ks = 0; ks < KS; ks++) {
        short8 av[9];
        #pragma unroll
        for (int t9 = 0; t9 < 9; t9++) {
            short8 v = *(const short8*)(inPtr + (long)cell[t9] * IC + ks * 32 + quad * 8);
            av[t9] = okb[t9] ? v : zero8;      // reg-reg cndmask
        }
        #pragma unroll
        for (int nl = 0; nl < NL; nl++) {
            #pragma unroll
            for (int t9 = 0; t9 < 9; t9++) {
                short8 bf = *(const short8*)(wfrag + (((t9 * KS + ks) * NT + ntb + nl) * 64 + lane) * 8);
                if (t9 & 1) acc[nl][1] = __builtin_amdgcn_mfma_f32_16x16x32_bf16(av[t9], bf, acc[nl][1], 0, 0, 0);
                else        acc[nl][0] = __builtin_amdgcn_mfma_f32_16x16x32_bf16(av[t9], bf, acc[nl][0], 0, 0, 0);
            }
        }
    }

    const long rowBase = (long)p0 + quad * 4;   // D: row=(lane>>4)*4+reg
    #pragma unroll
    for (int nl = 0; nl < NL; nl++) {
        const int oc = (ntb + nl) * 16 + lm;
        const float bv = bias[oc];
        #pragma unroll
        for (int reg = 0; reg < 4; reg++)
            out[(rowBase + reg) * OC + oc] = acc[nl][0][reg] + acc[nl][1][reg] + bv;
    }
}

// ---------------------------------------------------------------------------
// 3x3 stride-1 pad-1 maxpool (-inf pad) + ReLU, NHWC. fp32 in; bf16 or fp32
// out (bf16 feeds the next conv's MFMA A-operand).
// ---------------------------------------------------------------------------
template<int C, int HH, int WW, bool BF16OUT>
__global__ __launch_bounds__(256) void maxpool3_relu(const float* __restrict__ in, void* __restrict__ outv) {
    constexpr int C4 = C / 4;
    int i = blockIdx.x * blockDim.x + threadIdx.x;
    if (i >= NB * HH * WW * C4) return;
    int c = i % C4;
    int x = (i / C4) % WW;
    int y = (i / (C4 * WW)) % HH;
    int b = i / (C4 * WW * HH);
    float4 m = make_float4(-3.0e38f, -3.0e38f, -3.0e38f, -3.0e38f);
    #pragma unroll
    for (int dy = -1; dy <= 1; dy++) {
        int yy = y + dy;
        if (yy < 0 || yy >= HH) continue;
        #pragma unroll
        for (int dx = -1; dx <= 1; dx++) {
            int xx = x + dx;
            if (xx < 0 || xx >= WW) continue;
            float4 v = ((const float4*)in)[((b * HH + yy) * WW + xx) * C4 + c];
            m.x = fmaxf(m.x, v.x);
            m.y = fmaxf(m.y, v.y);
            m.z = fmaxf(m.z, v.z);
            m.w = fmaxf(m.w, v.w);
        }
    }
    m.x = fmaxf(m.x, 0.f);
    m.y = fmaxf(m.y, 0.f);
    m.z = fmaxf(m.z, 0.f);
    m.w = fmaxf(m.w, 0.f);
    if (BF16OUT) {
        ushort4 o;
        o.x = f2bf(m.x); o.y = f2bf(m.y); o.z = f2bf(m.z); o.w = f2bf(m.w);
        ((ushort4*)outv)[i] = o;
    } else {
        ((float4*)outv)[i] = m;
    }
}

// ---------------------------------------------------------------------------
// LDS-tiled permute: in[b][pos][c] (NHWC pooled3 fp32, pos=480,c=128) ->
// xT[c*480+pos][b]. Both sides coalesced float4.
// ---------------------------------------------------------------------------
__global__ __launch_bounds__(256) void transpose_fc(const float* __restrict__ in, float* __restrict__ xT) {
    __shared__ float tile_s[32 * 16 * 17];    // [c_l][pos_l][b(pad 17)]
    const int pt = blockIdx.x % 30;
    const int ct = blockIdx.x / 30;
    const int pos0 = pt * 16, c0 = ct * 32;
    const int t = threadIdx.x;
    {
        const int b = t / 16, pl = t % 16;
        const float4* src = (const float4*)(in + ((long)(b * 480 + pos0 + pl)) * 128 + c0);
        #pragma unroll
        for (int q = 0; q < 8; q++) {
            float4 v = src[q];
            tile_s[((4 * q + 0) * 16 + pl) * 17 + b] = v.x;
            tile_s[((4 * q + 1) * 16 + pl) * 17 + b] = v.y;
            tile_s[((4 * q + 2) * 16 + pl) * 17 + b] = v.z;
            tile_s[((4 * q + 3) * 16 + pl) * 17 + b] = v.w;
        }
    }
    __syncthreads();
    {
        const int w = t / 64, l = t % 64;
        const int pl2 = l / 4, b4 = l % 4;
        #pragma unroll
        for (int i = 0; i < 8; i++) {
            int cl = w + 4 * i;
            const float* ls = &tile_s[(cl * 16 + pl2) * 17 + 4 * b4];
            float4 v = make_float4(ls[0], ls[1], ls[2], ls[3]);
            *(float4*)(xT + ((long)(c0 + cl) * 480 + pos0 + pl2) * 16 + 4 * b4) = v;
        }
    }
}

// ---------------------------------------------------------------------------
// FC main v2 (R12): 4-lane-per-oc groups + LDS-staged x.
// R11 post-mortem: thread<->oc made every weight load a 64-line gather
// (oc rows 245 KB apart -> 64 distinct segments/instr) and the "uniform" x
// reads scalarized into ~120 s_load chains (SMEM OOO -> lgkmcnt(0) serial).
// Measured ~34 us (1.8 TB/s on 63 MB). Here:
//  - thread t: group q=t>>2 owns oc {q+64s}, ksub=t&3 takes an interleaved
//    quarter of the 120-k chunk as float2. Per weight instr a 4-lane group
//    reads 32 CONTIGUOUS bytes -> 16 fully-consumed segments/wave (4x fewer,
//    aligned). Weights still read exactly once (63 MB).
//  - x chunk (7.5 KB) staged in LDS, row stride 20 floats: the 4 distinct
//    rows per ds_read_b128 (drow=2 -> dbank=8) land on disjoint bank
//    quartets -> conflict-free 16-way broadcast. Each b128 feeds 4 oc's
//    FMAs (FMA:DS = 16:1).
//  - all 60 float2 weight loads preloaded (static indices, ~215 VGPR,
//    launch_bounds(256,2) -> no spill at 2 waves/SIMD = the resident count).
//  - end: shfl_xor(1,2) reduce within each 4-lane group; ksub==0 writes.
//    partial layout identical to R11 -> fc_reduce unchanged.
// ---------------------------------------------------------------------------
__global__ __launch_bounds__(256, 2) void fc_main(const float* __restrict__ xT,
                                                  const float* __restrict__ fw,
                                                  float* __restrict__ partial)
{
    __shared__ float x_lds[120 * 20];          // row stride 20 floats (80 B)
    const int c    = blockIdx.x;               // 512 chunks of 120 k
    const int t    = threadIdx.x;
    const int q    = t >> 2;                   // oc group 0..63
    const int ksub = t & 3;                    // k-quarter within group
    const int k0   = c * FC_KC;

    // ---- issue all weight loads first (independent of LDS) ----
    float2 w[4][15];
    #pragma unroll
    for (int s = 0; s < 4; s++) {
        const float* wr = fw + (long)(q + 64 * s) * FC_K + k0 + ksub * 2;
        #pragma unroll
        for (int g = 0; g < 15; g++)
            w[s][g] = *(const float2*)(wr + g * 8);   // float2 #(4g+ksub)
    }

    // ---- stage x chunk into LDS (padded rows) ----
    for (int i = t; i < 480; i += 256) {               // 480 float4s
        int k = i >> 2, b4 = i & 3;
        float4 v = *(const float4*)(xT + ((long)(k0 + k)) * 16 + b4 * 4);
        *(float4*)(&x_lds[k * 20 + b4 * 4]) = v;
    }
    __syncthreads();

    float acc[4][16];
    #pragma unroll
    for (int s = 0; s < 4; s++)
        #pragma unroll
        for (int b = 0; b < 16; b++) acc[s][b] = 0.f;

    #pragma unroll
    for (int g = 0; g < 15; g++) {
        #pragma unroll
        for (int j = 0; j < 2; j++) {
            const int klbase = 8 * g + j;              // + 2*ksub at runtime
            const float* xr = &x_lds[(klbase + 2 * ksub) * 20];
            f32x4 xv[4];
            #pragma unroll
            for (int b4 = 0; b4 < 4; b4++)
                xv[b4] = *(const f32x4*)(xr + 4 * b4);
            #pragma unroll
            for (int s = 0; s < 4; s++) {
                const float wv = (j == 0) ? w[s][g].x : w[s][g].y;
                #pragma unroll
                for (int b4 = 0; b4 < 4; b4++)
                    #pragma unroll
                    for (int e = 0; e < 4; e++)
                        acc[s][b4 * 4 + e] = fmaf(wv, xv[b4][e], acc[s][b4 * 4 + e]);
            }
        }
    }

    // ---- reduce over the 4-lane group (ksub) ----
    #pragma unroll
    for (int s = 0; s < 4; s++)
        #pragma unroll
        for (int b = 0; b < 16; b++) {
            float v = acc[s][b];
            v += __shfl_xor(v, 1);
            v += __shfl_xor(v, 2);
            acc[s][b] = v;
        }

    if (ksub == 0) {
        #pragma unroll
        for (int s = 0; s < 4; s++) {
            const int oc = q + 64 * s;
            float4* pp = (float4*)(partial + ((long)c * 256 + oc) * 16);
            pp[0] = make_float4(acc[s][0],  acc[s][1],  acc[s][2],  acc[s][3]);
            pp[1] = make_float4(acc[s][4],  acc[s][5],  acc[s][6],  acc[s][7]);
            pp[2] = make_float4(acc[s][8],  acc[s][9],  acc[s][10], acc[s][11]);
            pp[3] = make_float4(acc[s][12], acc[s][13], acc[s][14], acc[s][15]);
        }
    }
}

// ---------------------------------------------------------------------------
// FC reduce: 256 blocks (one oc each) x 256 threads. Thread (b=t&15,
// stripe=t>>4) sums 32 chunks; 16x16 LDS tree finishes.
// ---------------------------------------------------------------------------
__global__ __launch_bounds__(256) void fc_reduce(const float* __restrict__ partial,
                                                 const float* __restrict__ fcb,
                                                 float* __restrict__ out)
{
    __shared__ float red[16][17];
    const int oc = blockIdx.x;             // 256
    const int ol = threadIdx.x & 15;       // b
    const int st = threadIdx.x >> 4;       // chunk stripe
    float s = 0.f;
    #pragma unroll
    for (int j = 0; j < 32; j++)           // c = st + 16*j covers 0..511
        s += partial[(long)(st + 16 * j) * 4096 + oc * 16 + ol];
    red[st][ol] = s;
    __syncthreads();
    if (threadIdx.x < 16) {
        float tot = fcb[oc];
        #pragma unroll
        for (int k = 0; k < 16; k++) tot += red[k][threadIdx.x];
        out[threadIdx.x * 256 + oc] = fmaxf(tot, 0.f);   // out[b][oc]
    }
}

// ---------------------------------------------------------------------------
extern "C" void kernel_launch(void* const* d_in, const int* in_sizes, int n_in,
                              void* d_out, int out_size, void* d_ws, size_t ws_size,
                              hipStream_t stream) {
    const float* input  = (const float*)d_in[0];
    const int*   coords = (const int*)d_in[1];
    const float* w1 = (const float*)d_in[2];
    const float* b1 = (const float*)d_in[3];
    const float* w2 = (const float*)d_in[4];
    const float* b2 = (const float*)d_in[5];
    const float* w3 = (const float*)d_in[6];
    const float* b3 = (const float*)d_in[7];
    const float* fcw = (const float*)d_in[8];
    const float* fcb = (const float*)d_in[9];
    float* outp = (float*)d_out;

    const int n_active = in_sizes[1] / 3;

    // ---- workspace layout (~63.7 MB total) ----
    char* ws = (char*)d_ws;
    unsigned short* wf1 = (unsigned short*)ws;            // 18,432 B
    unsigned short* wf2 = wf1 + 9216;                     // 36,864 B
    unsigned short* wf3 = wf2 + 18432;                    // 147,456 B
    unsigned short* inBf = (unsigned short*)(ws + 204800);        // 31,457,280 B (16*96*320*32 bf16)
    char* regA = ws + 204800 + 31457280;                  // 15,728,640 B
    char* regB = regA + 15728640;                         // 7,864,320 B
    float* partial = (float*)(regB + 7864320);            // 8,388,608 B (512*4096*4)

    // ping-pong aliasing (stream-ordered, each buffer dead before reuse):
    float*          conv1o  = (float*)regA;           // 15.73 MB fp32
    unsigned short* pool1bf = (unsigned short*)regB;   //  7.86 MB bf16
    float*          conv2o  = (float*)regA;           //  7.86 MB fp32
    unsigned short* pool2bf = (unsigned short*)regB;   //  3.93 MB bf16
    float*          conv3o  = (float*)regA;           //  3.93 MB fp32
    float*          pool3f  = (float*)regB;           //  3.93 MB fp32
    float*          xT      = (float*)regA;           //  3.93 MB fp32

    // zero dense bf16 input (31,457,280 B -- R7's bug was undersizing this),
    // then fused wfrag-prep + scatter-cast of active cells only.
    hipMemsetAsync(inBf, 0, 31457280, stream);
    const int scatterBlocks = (n_active * 4 + 255) / 256;
    setup_all<<<396 + scatterBlocks, 256, 0, stream>>>(w1, w2, w3, wf1, wf2, wf3,
                                                       coords, input, inBf, n_active);

    // conv1: (16,96,320,32)->(16,48,160,32); NT=2 NL=2 -> 7680 waves
    conv_mfma<32, 32, 2, 96, 320, 48, 160>
        <<<1920, 256, 0, stream>>>(inBf, wf1, b1, conv1o);
    maxpool3_relu<32, 48, 160, true><<<3840, 256, 0, stream>>>(conv1o, pool1bf);

    // conv2: (16,48,160,32)->(16,24,80,64); NT=4 NL=2 -> 3840 waves
    conv_mfma<32, 64, 2, 48, 160, 24, 80>
        <<<960, 256, 0, stream>>>(pool1bf, wf2, b2, conv2o);
    maxpool3_relu<64, 24, 80, true><<<1920, 256, 0, stream>>>(conv2o, pool2bf);

    // conv3: (16,24,80,64)->(16,12,40,128); NT=8 NL=2 -> 1920 waves
    conv_mfma<64, 128, 2, 24, 80, 12, 40>
        <<<480, 256, 0, stream>>>(pool2bf, wf3, b3, conv3o);
    maxpool3_relu<128, 12, 40, false><<<960, 256, 0, stream>>>(conv3o, pool3f);

    // flatten permute + FC (fp32, exact weights; read-once both streams)
    transpose_fc<<<120, 256, 0, stream>>>(pool3f, xT);
    fc_main<<<FC_NCHUNK, 256, 0, stream>>>(xT, fcw, partial);
    fc_reduce<<<256, 256, 0, stream>>>(partial, fcb, outp);
}

// Round 3
// 242.202 us; speedup vs baseline: 1.0230x; 1.0006x over previous
//
#include <hip/hip_runtime.h>

// Problem constants
#define NB 16
#define NH 96
#define NW 320
#define NCIN 32

#define FC_K 61440
#define FC_KC 480          // k per chunk (1920 B contiguous weight run per group)
#define FC_NKC 128         // 128 k-chunks x 4 oc-quads = 512 blocks = 2/CU

typedef __attribute__((ext_vector_type(8))) short short8;     // 8 bf16 (4 VGPRs)
typedef __attribute__((ext_vector_type(4))) float f32x4;

__device__ inline unsigned short f2bf(float f) {
    union { float f; unsigned int u; } v; v.f = f;
    unsigned int r = v.u + 0x7FFF + ((v.u >> 16) & 1);   // RNE
    return (unsigned short)(r >> 16);
}

// ---------------------------------------------------------------------------
// Fused setup kernel.
// Blocks [0,396): weight fragments OIHW fp32 -> MFMA B-operand bf16,
//   wf[((kk*NT + nt)*64 + lane)*8 + j], oc = nt*16+(lane&15),
//   ic = ks*32+(lane>>4)*8+j  [m91-verified map]
// Blocks [396,...): scatter+cast active cells from fp32 input into the
//   (memset-zeroed) dense bf16 input. Reads ONLY active cells (~25.6 MB).
//   4 threads per coord, 8 ch each; duplicates write identical bytes.
// ---------------------------------------------------------------------------
__global__ __launch_bounds__(256) void setup_all(const float* __restrict__ w1,
                                                 const float* __restrict__ w2,
                                                 const float* __restrict__ w3,
                                                 unsigned short* __restrict__ f1,
                                                 unsigned short* __restrict__ f2,
                                                 unsigned short* __restrict__ f3,
                                                 const int* __restrict__ coords,
                                                 const float* __restrict__ input,
                                                 unsigned short* __restrict__ inBf,
                                                 int n) {
    if (blockIdx.x < 396) {
        int i = blockIdx.x * 256 + threadIdx.x;
        if (i < 9216) {                       // conv1: IC=32 OC=32 NT=2 KS=1
            int j = i & 7, lane = (i >> 3) & 63, nt = (i >> 9) & 1, tap = i >> 10;
            int ic = ((lane >> 4) * 8) + j, oc = nt * 16 + (lane & 15);
            f1[i] = f2bf(w1[(oc * 32 + ic) * 9 + tap]);
        } else if (i < 27648) {               // conv2: IC=32 OC=64 NT=4 KS=1
            int v = i - 9216;
            int j = v & 7, lane = (v >> 3) & 63, nt = (v >> 9) & 3, tap = v >> 11;
            int ic = ((lane >> 4) * 8) + j, oc = nt * 16 + (lane & 15);
            f2[v] = f2bf(w2[(oc * 32 + ic) * 9 + tap]);
        } else if (i < 101376) {              // conv3: IC=64 OC=128 NT=8 KS=2
            int v = i - 27648;
            int j = v & 7, lane = (v >> 3) & 63, nt = (v >> 9) & 7, kk = v >> 12;
            int tap = kk >> 1, ks = kk & 1;
            int ic = ks * 32 + ((lane >> 4) * 8) + j, oc = nt * 16 + (lane & 15);
            f3[v] = f2bf(w3[(oc * 64 + ic) * 9 + tap]);
        }
    } else {
        int i = (blockIdx.x - 396) * 256 + threadIdx.x;
        if (i >= n * 4) return;
        int ci = i >> 2, q = i & 3;
        int b = coords[ci * 3 + 0], y = coords[ci * 3 + 1], x = coords[ci * 3 + 2];
        long base = ((long)((b * NH + y) * NW + x)) * NCIN + q * 8;
        const float4* src = (const float4*)(input + base);
        float4 v0 = src[0], v1 = src[1];
        union { short8 s8; unsigned short us[8]; } o;
        o.us[0] = f2bf(v0.x); o.us[1] = f2bf(v0.y); o.us[2] = f2bf(v0.z); o.us[3] = f2bf(v0.w);
        o.us[4] = f2bf(v1.x); o.us[5] = f2bf(v1.y); o.us[6] = f2bf(v1.z); o.us[7] = f2bf(v1.w);
        *(short8*)(inBf + base) = o.s8;
    }
}

// ---------------------------------------------------------------------------
// Implicit-GEMM conv 3x3 stride-2 pad-1 via bf16 MFMA (16x16x32), bf16 NHWC in.
// Each wave: one 16-position strip x NL oc-tiles. A-fragments loaded ONCE
// per ks (9 x 16 B/lane, unconditional, addr clamped to cell 0, reg-reg
// cndmask -- R8 lesson), reused for NL*9 MFMAs (R9/R10 lesson: oc-tile
// duplication of the scattered gather was the stall). B-frag loads coalesced
// 1KB/wave, L1-hot, in-loop. acc indices compile-time (R4), ks loop unroll 1
// (R2). Layouts m89/m91: A[m=lane&15][k=quad*8+j], D[row=quad*4+reg][col=lane&15].
// ---------------------------------------------------------------------------
template<int IC, int OC, int NL, int IH, int IW, int OH, int OW>
__global__ __launch_bounds__(256) void conv_mfma(
    const unsigned short* __restrict__ inPtr,  // NHWC bf16
    const unsigned short* __restrict__ wfrag,  // B-fragments bf16
    const float* __restrict__ bias,
    float* __restrict__ out)                   // NHWC fp32 (pre-relu)
{
    constexpr int KS = IC / 32;
    constexpr int NT = OC / 16;
    constexpr int NG = NT / NL;                // wave-groups per strip
    constexpr int NSTRIPS = NB * OH * OW / 16;

    const int wid  = (blockIdx.x * 256 + threadIdx.x) >> 6;
    const int lane = threadIdx.x & 63;
    const int ntb  = (wid % NG) * NL;
    const int s    = wid / NG;
    if (s >= NSTRIPS) return;
    const int quad = lane >> 4;
    const int lm   = lane & 15;

    const int p0 = s * 16;
    const int posA = p0 + lm;
    const int b  = posA / (OH * OW);
    const int rr = posA % (OH * OW);
    const int oy = rr / OW, ox = rr % OW;
    const int iy0 = oy * 2 - 1, ix0 = ox * 2 - 1;

    int cell[9];
    bool okb[9];
    #pragma unroll
    for (int t9 = 0; t9 < 9; t9++) {
        const int iy = iy0 + t9 / 3;
        const int ix = ix0 + t9 % 3;
        const bool ok = (iy >= 0) && (iy < IH) && (ix >= 0) && (ix < IW);
        cell[t9] = ok ? ((b * IH + iy) * IW + ix) : 0;   // clamp addr, not load
        okb[t9] = ok;
    }

    short8 zero8;
    #pragma unroll
    for (int j = 0; j < 8; j++) zero8[j] = 0;

    f32x4 acc[NL][2];
    #pragma unroll
    for (int nl = 0; nl < NL; nl++)
        #pragma unroll
        for (int pp = 0; pp < 2; pp++)
            acc[nl][pp] = (f32x4){0.f, 0.f, 0.f, 0.f};

    #pragma unroll 1
    for (int ks = 0; ks < KS; ks++) {
        short8 av[9];
        #pragma unroll
        for (int t9 = 0; t9 < 9; t9++) {
            short8 v = *(const short8*)(inPtr + (long)cell[t9] * IC + ks * 32 + quad * 8);
            av[t9] = okb[t9] ? v : zero8;      // reg-reg cndmask
        }
        #pragma unroll
        for (int nl = 0; nl < NL; nl++) {
            #pragma unroll
            for (int t9 = 0; t9 < 9; t9++) {
                short8 bf = *(const short8*)(wfrag + (((t9 * KS + ks) * NT + ntb + nl) * 64 + lane) * 8);
                if (t9 & 1) acc[nl][1] = __builtin_amdgcn_mfma_f32_16x16x32_bf16(av[t9], bf, acc[nl][1], 0, 0, 0);
                else        acc[nl][0] = __builtin_amdgcn_mfma_f32_16x16x32_bf16(av[t9], bf, acc[nl][0], 0, 0, 0);
            }
        }
    }

    const long rowBase = (long)p0 + quad * 4;   // D: row=(lane>>4)*4+reg
    #pragma unroll
    for (int nl = 0; nl < NL; nl++) {
        const int oc = (ntb + nl) * 16 + lm;
        const float bv = bias[oc];
        #pragma unroll
        for (int reg = 0; reg < 4; reg++)
            out[(rowBase + reg) * OC + oc] = acc[nl][0][reg] + acc[nl][1][reg] + bv;
    }
}

// ---------------------------------------------------------------------------
// 3x3 stride-1 pad-1 maxpool (-inf pad) + ReLU, NHWC. fp32 in; bf16 or fp32
// out (bf16 feeds the next conv's MFMA A-operand).
// ---------------------------------------------------------------------------
template<int C, int HH, int WW, bool BF16OUT>
__global__ __launch_bounds__(256) void maxpool3_relu(const float* __restrict__ in, void* __restrict__ outv) {
    constexpr int C4 = C / 4;
    int i = blockIdx.x * blockDim.x + threadIdx.x;
    if (i >= NB * HH * WW * C4) return;
    int c = i % C4;
    int x = (i / C4) % WW;
    int y = (i / (C4 * WW)) % HH;
    int b = i / (C4 * WW * HH);
    float4 m = make_float4(-3.0e38f, -3.0e38f, -3.0e38f, -3.0e38f);
    #pragma unroll
    for (int dy = -1; dy <= 1; dy++) {
        int yy = y + dy;
        if (yy < 0 || yy >= HH) continue;
        #pragma unroll
        for (int dx = -1; dx <= 1; dx++) {
            int xx = x + dx;
            if (xx < 0 || xx >= WW) continue;
            float4 v = ((const float4*)in)[((b * HH + yy) * WW + xx) * C4 + c];
            m.x = fmaxf(m.x, v.x);
            m.y = fmaxf(m.y, v.y);
            m.z = fmaxf(m.z, v.z);
            m.w = fmaxf(m.w, v.w);
        }
    }
    m.x = fmaxf(m.x, 0.f);
    m.y = fmaxf(m.y, 0.f);
    m.z = fmaxf(m.z, 0.f);
    m.w = fmaxf(m.w, 0.f);
    if (BF16OUT) {
        ushort4 o;
        o.x = f2bf(m.x); o.y = f2bf(m.y); o.z = f2bf(m.z); o.w = f2bf(m.w);
        ((ushort4*)outv)[i] = o;
    } else {
        ((float4*)outv)[i] = m;
    }
}

// ---------------------------------------------------------------------------
// LDS-tiled permute: in[b][pos][c] (NHWC pooled3 fp32, pos=480,c=128) ->
// xT[c*480+pos][b]. Both sides coalesced float4.
// ---------------------------------------------------------------------------
__global__ __launch_bounds__(256) void transpose_fc(const float* __restrict__ in, float* __restrict__ xT) {
    __shared__ float tile_s[32 * 16 * 17];    // [c_l][pos_l][b(pad 17)]
    const int pt = blockIdx.x % 30;
    const int ct = blockIdx.x / 30;
    const int pos0 = pt * 16, c0 = ct * 32;
    const int t = threadIdx.x;
    {
        const int b = t / 16, pl = t % 16;
        const float4* src = (const float4*)(in + ((long)(b * 480 + pos0 + pl)) * 128 + c0);
        #pragma unroll
        for (int q = 0; q < 8; q++) {
            float4 v = src[q];
            tile_s[((4 * q + 0) * 16 + pl) * 17 + b] = v.x;
            tile_s[((4 * q + 1) * 16 + pl) * 17 + b] = v.y;
            tile_s[((4 * q + 2) * 16 + pl) * 17 + b] = v.z;
            tile_s[((4 * q + 3) * 16 + pl) * 17 + b] = v.w;
        }
    }
    __syncthreads();
    {
        const int w = t / 64, l = t % 64;
        const int pl2 = l / 4, b4 = l % 4;
        #pragma unroll
        for (int i = 0; i < 8; i++) {
            int cl = w + 4 * i;
            const float* ls = &tile_s[(cl * 16 + pl2) * 17 + 4 * b4];
            float4 v = make_float4(ls[0], ls[1], ls[2], ls[3]);
            *(float4*)(xT + ((long)(c0 + cl) * 480 + pos0 + pl2) * 16 + 4 * b4) = v;
        }
    }
}

// ---------------------------------------------------------------------------
// FC main v3 (R13): long-granule weight streams + LDS-broadcast x.
// Post-mortems: v0 (coalesced weights, 64x xT LLC re-read) = 41 us; v1
// (480 B/thread weight granules) ~34; v2 (480 B/group granules, 32 B
// half-line requests) ~33. Common failure: 63 MB read in ~131k scattered
// sub-KB streams -> HBM collapses to ~1.9 TB/s (sequential fillBuffer on
// this chip: 6.6 TB/s). v3 fixes BOTH streams at once:
//  - 512 blocks = 4 oc-quads x 128 k-chunks, KC=480. Thread t: group
//    q=t>>2 owns oc=ocb*64+q, ksub=t&3. Per float4 load a 4-lane group
//    covers exactly one 64 B line; its 30 loads walk a CONTIGUOUS 1920 B
//    run. No half-line requests, 4x granule. Weights still read once.
//  - x chunk 480x16 staged in LDS (30 KB, stride 20: b128-aligned, ksub
//    lanes 2-way on banks = free per m136). Each b128 broadcasts to 16
//    groups; FMA:DS = 4:1, both hidden under the weight stream.
//  - partial shrinks to 2 MB (128 chunks); acc[16] only -> ~170 VGPR,
//    launch_bounds(256,2), 2 blocks/CU balanced.
// ---------------------------------------------------------------------------
__global__ __launch_bounds__(256, 2) void fc_main(const float* __restrict__ xT,
                                                  const float* __restrict__ fw,
                                                  float* __restrict__ partial)
{
    __shared__ float x_lds[480 * 20];          // stride 20 floats (80 B, 16B-aligned)
    const int bx   = blockIdx.x;
    const int kc   = bx & 127;                 // k-chunk 0..127
    const int ocb  = bx >> 7;                  // oc-quad 0..3
    const int t    = threadIdx.x;
    const int q    = t >> 2;                   // oc group 0..63
    const int ksub = t & 3;
    const int k0   = kc * FC_KC;
    const int oc   = ocb * 64 + q;

    // ---- weight preload: 30 float4; 4-lane group = one 64 B line per load,
    //      30 loads = 1920 B contiguous run ----
    const float* wr = fw + (long)oc * FC_K + k0 + ksub * 4;
    f32x4 w[30];
    #pragma unroll
    for (int g = 0; g < 30; g++)
        w[g] = *(const f32x4*)(wr + g * 16);

    // ---- stage x[480][16] into LDS (padded stride 20) ----
    for (int i = t; i < 1920; i += 256) {
        int k = i >> 2, b4 = i & 3;
        *(float4*)(&x_lds[k * 20 + b4 * 4]) =
            *(const float4*)(xT + ((long)(k0 + k)) * 16 + b4 * 4);
    }
    __syncthreads();

    float acc[16];
    #pragma unroll
    for (int b = 0; b < 16; b++) acc[b] = 0.f;

    #pragma unroll
    for (int g = 0; g < 30; g++) {
        #pragma unroll
        for (int e = 0; e < 4; e++) {
            const float wv = w[g][e];                           // k = k0+g*16+ksub*4+e
            const float* xr = &x_lds[(g * 16 + ksub * 4 + e) * 20];
            f32x4 xv[4];
            #pragma unroll
            for (int b4 = 0; b4 < 4; b4++)
                xv[b4] = *(const f32x4*)(xr + 4 * b4);
            #pragma unroll
            for (int b4 = 0; b4 < 4; b4++)
                #pragma unroll
                for (int el = 0; el < 4; el++)
                    acc[b4 * 4 + el] = fmaf(wv, xv[b4][el], acc[b4 * 4 + el]);
        }
    }

    // ---- reduce over the 4-lane group (ksub) ----
    #pragma unroll
    for (int b = 0; b < 16; b++) {
        float v = acc[b];
        v += __shfl_xor(v, 1);
        v += __shfl_xor(v, 2);
        acc[b] = v;
    }

    if (ksub == 0) {
        float4* pp = (float4*)(partial + ((long)kc * 256 + oc) * 16);
        pp[0] = make_float4(acc[0],  acc[1],  acc[2],  acc[3]);
        pp[1] = make_float4(acc[4],  acc[5],  acc[6],  acc[7]);
        pp[2] = make_float4(acc[8],  acc[9],  acc[10], acc[11]);
        pp[3] = make_float4(acc[12], acc[13], acc[14], acc[15]);
    }
}

// ---------------------------------------------------------------------------
// FC reduce: 256 blocks (one oc each) x 256 threads. Thread (b=t&15,
// stripe=t>>4) sums 8 chunks; 16x16 LDS tree finishes. 2 MB total read.
// ---------------------------------------------------------------------------
__global__ __launch_bounds__(256) void fc_reduce(const float* __restrict__ partial,
                                                 const float* __restrict__ fcb,
                                                 float* __restrict__ out)
{
    __shared__ float red[16][17];
    const int oc = blockIdx.x;             // 256
    const int ol = threadIdx.x & 15;       // b
    const int st = threadIdx.x >> 4;       // chunk stripe
    float s = 0.f;
    #pragma unroll
    for (int j = 0; j < 8; j++)            // c = st + 16*j covers 0..127
        s += partial[(long)(st + 16 * j) * 4096 + oc * 16 + ol];
    red[st][ol] = s;
    __syncthreads();
    if (threadIdx.x < 16) {
        float tot = fcb[oc];
        #pragma unroll
        for (int k = 0; k < 16; k++) tot += red[k][threadIdx.x];
        out[threadIdx.x * 256 + oc] = fmaxf(tot, 0.f);   // out[b][oc]
    }
}

// ---------------------------------------------------------------------------
extern "C" void kernel_launch(void* const* d_in, const int* in_sizes, int n_in,
                              void* d_out, int out_size, void* d_ws, size_t ws_size,
                              hipStream_t stream) {
    const float* input  = (const float*)d_in[0];
    const int*   coords = (const int*)d_in[1];
    const float* w1 = (const float*)d_in[2];
    const float* b1 = (const float*)d_in[3];
    const float* w2 = (const float*)d_in[4];
    const float* b2 = (const float*)d_in[5];
    const float* w3 = (const float*)d_in[6];
    const float* b3 = (const float*)d_in[7];
    const float* fcw = (const float*)d_in[8];
    const float* fcb = (const float*)d_in[9];
    float* outp = (float*)d_out;

    const int n_active = in_sizes[1] / 3;

    // ---- workspace layout (~57.4 MB total) ----
    char* ws = (char*)d_ws;
    unsigned short* wf1 = (unsigned short*)ws;            // 18,432 B
    unsigned short* wf2 = wf1 + 9216;                     // 36,864 B
    unsigned short* wf3 = wf2 + 18432;                    // 147,456 B
    unsigned short* inBf = (unsigned short*)(ws + 204800);        // 31,457,280 B (16*96*320*32 bf16)
    char* regA = ws + 204800 + 31457280;                  // 15,728,640 B
    char* regB = regA + 15728640;                         // 7,864,320 B
    float* partial = (float*)(regB + 7864320);            // 2,097,152 B (128*256*16*4)

    // ping-pong aliasing (stream-ordered, each buffer dead before reuse):
    float*          conv1o  = (float*)regA;           // 15.73 MB fp32
    unsigned short* pool1bf = (unsigned short*)regB;   //  7.86 MB bf16
    float*          conv2o  = (float*)regA;           //  7.86 MB fp32
    unsigned short* pool2bf = (unsigned short*)regB;   //  3.93 MB bf16
    float*          conv3o  = (float*)regA;           //  3.93 MB fp32
    float*          pool3f  = (float*)regB;           //  3.93 MB fp32
    float*          xT      = (float*)regA;           //  3.93 MB fp32

    // zero dense bf16 input (31,457,280 B -- R7's bug was undersizing this),
    // then fused wfrag-prep + scatter-cast of active cells only.
    hipMemsetAsync(inBf, 0, 31457280, stream);
    const int scatterBlocks = (n_active * 4 + 255) / 256;
    setup_all<<<396 + scatterBlocks, 256, 0, stream>>>(w1, w2, w3, wf1, wf2, wf3,
                                                       coords, input, inBf, n_active);

    // conv1: (16,96,320,32)->(16,48,160,32); NT=2 NL=2 -> 7680 waves
    conv_mfma<32, 32, 2, 96, 320, 48, 160>
        <<<1920, 256, 0, stream>>>(inBf, wf1, b1, conv1o);
    maxpool3_relu<32, 48, 160, true><<<3840, 256, 0, stream>>>(conv1o, pool1bf);

    // conv2: (16,48,160,32)->(16,24,80,64); NT=4 NL=2 -> 3840 waves
    conv_mfma<32, 64, 2, 48, 160, 24, 80>
        <<<960, 256, 0, stream>>>(pool1bf, wf2, b2, conv2o);
    maxpool3_relu<64, 24, 80, true><<<1920, 256, 0, stream>>>(conv2o, pool2bf);

    // conv3: (16,24,80,64)->(16,12,40,128); NT=8 NL=2 -> 1920 waves
    conv_mfma<64, 128, 2, 24, 80, 12, 40>
        <<<480, 256, 0, stream>>>(pool2bf, wf3, b3, conv3o);
    maxpool3_relu<128, 12, 40, false><<<960, 256, 0, stream>>>(conv3o, pool3f);

    // flatten permute + FC (fp32, exact weights; read-once long streams)
    transpose_fc<<<120, 256, 0, stream>>>(pool3f, xT);
    fc_main<<<4 * FC_NKC, 256, 0, stream>>>(xT, fcw, partial);
    fc_reduce<<<256, 256, 0, stream>>>(partial, fcb, outp);
}